// Round 22
// baseline (91.878 us; speedup 1.0000x reference)
//
#include <hip/hip_runtime.h>

#define NB 2
#define NH 8
#define NS 2048
#define ND 64
#define WKT 64              // pass-B keys per wave-tile
#define NTW 8               // pass-B tiles per wave (512 / 64)
#define WKA 128             // pass-A keys per wave-tile
#define NTA 4               // pass-A tiles per wave (512 / 128)
#define QST 68              // LDS strides (f16 elems)
#define KST 76
#define VST 68
#define PST 68
#define OST 68              // f32
#define QSCALE 0.18033688f  // 0.125 * log2(e): folds 1/T and exp->exp2

typedef _Float16 f16x4 __attribute__((ext_vector_type(4)));
typedef _Float16 f16x8 __attribute__((ext_vector_type(8)));
typedef float    f32x4 __attribute__((ext_vector_type(4)));

#define MFMA16(A,B,C) __builtin_amdgcn_mfma_f32_16x16x32_f16((A),(B),(C),0,0,0)

static __device__ __forceinline__ f16x8 cat8(f16x4 a, f16x4 b) {
    return __builtin_shufflevector(a, b, 0, 1, 2, 3, 4, 5, 6, 7);
}
static __device__ __forceinline__ f16x4 tof16(float4 f) {
    return (f16x4){ (_Float16)f.x, (_Float16)f.y, (_Float16)f.z, (_Float16)f.w };
}
static __device__ __forceinline__ f16x8 lds8(const _Float16* p) {
    f16x4 a = *(const f16x4*)p;          // ds_read_b64 pair
    f16x4 b = *(const f16x4*)(p + 4);
    return cat8(a, b);
}
// 2^x via compiler intrinsic (raw asm omits TRANS hazard waits -> NaN, r20)
static __device__ __forceinline__ float fexp2(float x) {
    return __builtin_amdgcn_exp2f(x);
}
// wave-local staging fence: wait own LDS ops, pin DS reordering only
static __device__ __forceinline__ void dsfence() {
    asm volatile("s_waitcnt lgkmcnt(0)");
    __builtin_amdgcn_sched_barrier(0x7F);
}

__global__ __launch_bounds__(256, 2)
void sdpa_kernel(const float* __restrict__ Qg, const float* __restrict__ Kg,
                 const float* __restrict__ Vg, float* __restrict__ Og,
                 float* __restrict__ Ag)
{
    const int tid  = threadIdx.x;
    const int w    = tid >> 6;
    const int lane = tid & 63;
    const int lg   = lane >> 4;
    const int lc   = lane & 15;

    // XCD-pinned decode (proven: FETCH 103->12 MB): bid&7 = XCD, 2 heads/XCD.
    const int bid = blockIdx.x;
    const int xcd = bid & 7;
    const int j   = bid >> 3;           // 0..63
    const int bh  = 2 * xcd + (j >> 5); // 0..15
    const int qt_ = j & 31;             // 0..31

    const size_t base = (size_t)bh * NS * ND;
    const float* Qp = Qg + base + (size_t)qt_ * 64 * ND;
    const float* Kp = Kg + base;
    const float* Vp = Vg + base;
    float*       Op = Og + base + (size_t)qt_ * 64 * ND;
    float*       Ap = Ag + (size_t)bh * NS * NS + (size_t)qt_ * 64 * NS;

    // pool 77824 B (2 blocks/CU):
    //   pass A: KA[w] = pool + w*19456 (128 rows x KST76)
    //   pass B: KV[w] = pool + w*9728 (K 64xKST76 / VT 64xVST68 time-shared),
    //           Ps[w] = pool + 38912 + w*8704
    //   overlays: Qs (prologue), MLs (inter-pass, at 38912), Obuf (epilogue)
    __shared__ __align__(16) unsigned char pool[77824];
    _Float16* Qs = (_Float16*)pool;                            // prologue only
    _Float16* KA = (_Float16*)(pool + (size_t)w * 19456);
    _Float16* KV = (_Float16*)(pool + (size_t)w * 9728);
    _Float16* Ps = (_Float16*)(pool + 38912 + (size_t)w * 8704);
    float*   MLs = (float*)(pool + 38912);                     // inter-pass
    float*  Obuf = (float*)pool;                               // epilogue

    // ---- stage Q (scaled by QSCALE = 1/T * log2e) cooperatively ----
    {
        const int srow = tid >> 4, sd0 = (tid & 15) * 4;
        #pragma unroll
        for (int it = 0; it < 4; ++it) {
            const int r = srow + 16 * it;
            float4 f = *(const float4*)&Qp[(size_t)r * ND + sd0];
            f16x4 h = { (_Float16)(f.x * QSCALE), (_Float16)(f.y * QSCALE),
                        (_Float16)(f.z * QSCALE), (_Float16)(f.w * QSCALE) };
            *(f16x4*)&Qs[r * QST + sd0] = h;
        }
    }
    __syncthreads();
    f16x8 qfa[4], qfb[4];        // every wave needs all 64 q columns
    #pragma unroll
    for (int qt = 0; qt < 4; ++qt) {
        qfa[qt] = lds8(&Qs[(16 * qt + lc) * QST + 8 * lg]);
        qfb[qt] = lds8(&Qs[(16 * qt + lc) * QST + 8 * lg + 32]);
    }
    __syncthreads();             // Qs dead; KA overlays it

    const int vkq = lane >> 3;   // V staging: key quad 4*vkq (within 32-half)
    const int vdg = lane & 7;    // V staging: d group 8*vdg

    float lacc[4] = {0.f, 0.f, 0.f, 0.f};

    // ============ PASS A: denominators, WKA=128 (4 big phases) ============
    {
        float4 ka[8], kb[8], kc4[8], kd[8];
        for (int t = 0; t < NTA; ++t) {
            const int koff = 512 * w + WKA * t;
            // issue ALL 32 loads (128 rows) before any cvt -> one vmcnt stall
            #pragma unroll
            for (int i = 0; i < 8; ++i)
                ka[i] = *(const float4*)&Kp[(size_t)koff * ND + i * 256 + 4 * lane];
            #pragma unroll
            for (int i = 0; i < 8; ++i)
                kb[i] = *(const float4*)&Kp[(size_t)koff * ND + 2048 + i * 256 + 4 * lane];
            #pragma unroll
            for (int i = 0; i < 8; ++i)
                kc4[i] = *(const float4*)&Kp[(size_t)koff * ND + 4096 + i * 256 + 4 * lane];
            #pragma unroll
            for (int i = 0; i < 8; ++i)
                kd[i] = *(const float4*)&Kp[(size_t)koff * ND + 6144 + i * 256 + 4 * lane];
            #pragma unroll
            for (int i = 0; i < 8; ++i)
                *(f16x4*)&KA[(4 * i + lg) * KST + 4 * lc] = tof16(ka[i]);
            #pragma unroll
            for (int i = 0; i < 8; ++i)
                *(f16x4*)&KA[(32 + 4 * i + lg) * KST + 4 * lc] = tof16(kb[i]);
            #pragma unroll
            for (int i = 0; i < 8; ++i)
                *(f16x4*)&KA[(64 + 4 * i + lg) * KST + 4 * lc] = tof16(kc4[i]);
            #pragma unroll
            for (int i = 0; i < 8; ++i)
                *(f16x4*)&KA[(96 + 4 * i + lg) * KST + 4 * lc] = tof16(kd[i]);
            dsfence();

            __builtin_amdgcn_s_setprio(1);
            #pragma unroll
            for (int mt = 0; mt < 8; ++mt) {
                f16x8 a0 = lds8(&KA[(16 * mt + lc) * KST + 8 * lg]);
                f16x8 a1 = lds8(&KA[(16 * mt + lc) * KST + 8 * lg + 32]);
                #pragma unroll
                for (int qt = 0; qt < 4; ++qt) {
                    f32x4 z = {0.f, 0.f, 0.f, 0.f};
                    z = MFMA16(a0, qfa[qt], z);
                    z = MFMA16(a1, qfb[qt], z);
                    #pragma unroll
                    for (int r = 0; r < 4; ++r)
                        lacc[qt] += fexp2(z[r]);
                }
            }
            __builtin_amdgcn_s_setprio(0);
            __builtin_amdgcn_sched_barrier(0x7F);   // reads before next writes
        }
    }

    // ---- merge denominators across waves (max-free softmax) ----
    #pragma unroll
    for (int qt = 0; qt < 4; ++qt) {
        lacc[qt] += __shfl_xor(lacc[qt], 16);
        lacc[qt] += __shfl_xor(lacc[qt], 32);
    }
    __syncthreads();             // KA reads done everywhere; MLs region free
    if (lg == 0) {
        #pragma unroll
        for (int qt = 0; qt < 4; ++qt)
            MLs[w * 64 + 16 * qt + lc] = lacc[qt];
    }
    __syncthreads();
    float il[4];
    #pragma unroll
    for (int qt = 0; qt < 4; ++qt)
        il[qt] = 1.0f / (MLs[16 * qt + lc] + MLs[64 + 16 * qt + lc] +
                         MLs[128 + 16 * qt + lc] + MLs[192 + 16 * qt + lc]);
    __syncthreads();             // MLs dead; Ps overlays it

    // ============ PASS B: attn write + PV (r21 + K-prefetch rotation) ============
    f32x4 acc[4][4];             // [dt][qt]
    #pragma unroll
    for (int dt = 0; dt < 4; ++dt)
        #pragma unroll
        for (int qt = 0; qt < 4; ++qt)
            acc[dt][qt] = {0.f, 0.f, 0.f, 0.f};

    float4 kr0[8], kr1[8];
    auto loadK = [&](int koff) {
        #pragma unroll
        for (int i = 0; i < 8; ++i)
            kr0[i] = *(const float4*)&Kp[(size_t)koff * ND + i * 256 + 4 * lane];
        #pragma unroll
        for (int i = 0; i < 8; ++i)
            kr1[i] = *(const float4*)&Kp[(size_t)koff * ND + 2048 + i * 256 + 4 * lane];
    };
    auto writeK = [&]() {
        #pragma unroll
        for (int i = 0; i < 8; ++i)
            *(f16x4*)&KV[(4 * i + lg) * KST + 4 * lc] = tof16(kr0[i]);
        #pragma unroll
        for (int i = 0; i < 8; ++i)
            *(f16x4*)&KV[(32 + 4 * i + lg) * KST + 4 * lc] = tof16(kr1[i]);
    };

    loadK(512 * w);              // prologue: prefetch tile 0
    for (int t = 0; t < NTW; ++t) {
        const int koff = 512 * w + WKT * t;
        writeK();                // consumes kr loaded LAST tile: no vmcnt stall
        loadK(512 * w + WKT * (t + 1 < NTW ? t + 1 : 0));  // prefetch next
        // ---- issue V loads for both 32-key halves (land during QK^T) ----
        float4 vr0[8], vr1[8];
        #pragma unroll
        for (int r = 0; r < 4; ++r)
            #pragma unroll
            for (int h = 0; h < 2; ++h) {
                vr0[2 * r + h] = *(const float4*)
                    &Vp[(size_t)(koff + 4 * vkq + r) * ND + 8 * vdg + 4 * h];
                vr1[2 * r + h] = *(const float4*)
                    &Vp[(size_t)(koff + 32 + 4 * vkq + r) * ND + 8 * vdg + 4 * h];
            }
        dsfence();               // K writes visible to own reads

        // ---- QK^T -> 2^z -> Ps (per-mt fused, low VGPR) ----
        __builtin_amdgcn_s_setprio(1);
        #pragma unroll
        for (int mt = 0; mt < 4; ++mt) {
            f16x8 a0 = lds8(&KV[(16 * mt + lc) * KST + 8 * lg]);
            f16x8 a1 = lds8(&KV[(16 * mt + lc) * KST + 8 * lg + 32]);
            #pragma unroll
            for (int qt = 0; qt < 4; ++qt) {
                f32x4 z = {0.f, 0.f, 0.f, 0.f};
                z = MFMA16(a0, qfa[qt], z);
                z = MFMA16(a1, qfb[qt], z);
                f32x4 p;
                #pragma unroll
                for (int r = 0; r < 4; ++r)
                    p[r] = fexp2(z[r]) * il[qt];
                f16x4 ph = { (_Float16)p[0], (_Float16)p[1],
                             (_Float16)p[2], (_Float16)p[3] };
                *(f16x4*)&Ps[(16 * qt + lc) * PST + 16 * mt + 4 * lg] = ph;
            }
        }
        __builtin_amdgcn_s_setprio(0);

        // ---- VT writes into KV (after QK's last read; wave-local DS in-order) ----
        #pragma unroll
        for (int h = 0; h < 2; ++h)
            #pragma unroll
            for (int jj = 0; jj < 4; ++jj) {
                f16x4 c0 = { (_Float16)vr0[0 + h][jj], (_Float16)vr0[2 + h][jj],
                             (_Float16)vr0[4 + h][jj], (_Float16)vr0[6 + h][jj] };
                *(f16x4*)&KV[(8 * vdg + 4 * h + jj) * VST + 4 * vkq] = c0;
                f16x4 c1 = { (_Float16)vr1[0 + h][jj], (_Float16)vr1[2 + h][jj],
                             (_Float16)vr1[4 + h][jj], (_Float16)vr1[6 + h][jj] };
                *(f16x4*)&KV[(8 * vdg + 4 * h + jj) * VST + 32 + 4 * vkq] = c1;
            }
        dsfence();               // Ps + VT visible to own reads

        // ---- PV: O^T += V^T . P^T (two 32-key slices) ----
        f16x8 bfa[4], bfb[4];
        #pragma unroll
        for (int qt = 0; qt < 4; ++qt) {
            bfa[qt] = lds8(&Ps[(16 * qt + lc) * PST + 8 * lg]);
            bfb[qt] = lds8(&Ps[(16 * qt + lc) * PST + 32 + 8 * lg]);
        }
        __builtin_amdgcn_s_setprio(1);
        #pragma unroll
        for (int dt = 0; dt < 4; ++dt) {
            f16x8 af0 = lds8(&KV[(16 * dt + lc) * VST + 8 * lg]);
            f16x8 af1 = lds8(&KV[(16 * dt + lc) * VST + 32 + 8 * lg]);
            #pragma unroll
            for (int qt = 0; qt < 4; ++qt) {
                acc[dt][qt] = MFMA16(af0, bfa[qt], acc[dt][qt]);
                acc[dt][qt] = MFMA16(af1, bfb[qt], acc[dt][qt]);
            }
        }
        __builtin_amdgcn_s_setprio(0);

        // ---- attn store: Ps readback, cvt, 256B/row, sequential across tiles ----
        #pragma unroll
        for (int i = 0; i < 16; ++i) {
            const int qr = 4 * i + (lane >> 4);    // 0..63
            const int kc = 4 * (lane & 15);        // 0..60
            f16x4 ph = *(const f16x4*)&Ps[qr * PST + kc];
            f32x4 pf = { (float)ph[0], (float)ph[1], (float)ph[2], (float)ph[3] };
            *(f32x4*)&Ap[(size_t)qr * NS + koff + kc] = pf;
        }
        __builtin_amdgcn_sched_barrier(0x7F);   // reads precede next-tile writes
    }

    // ---- merge partial O across waves (sequential LDS accumulate), store ----
    __syncthreads();             // main-loop LDS dead; Obuf overlays
    #pragma unroll
    for (int ww = 0; ww < 4; ++ww) {
        if (w == ww) {
            #pragma unroll
            for (int dt = 0; dt < 4; ++dt)
                #pragma unroll
                for (int qt = 0; qt < 4; ++qt) {
                    float* ad = &Obuf[(16 * qt + lc) * OST + 16 * dt + 4 * lg];
                    f32x4 v = acc[dt][qt];
                    if (ww > 0) v = v + *(const f32x4*)ad;
                    *(f32x4*)ad = v;
                }
        }
        __syncthreads();
    }
    #pragma unroll
    for (int dt = 0; dt < 4; ++dt) {
        f32x4 o = *(const f32x4*)&Obuf[(16 * w + lc) * OST + 16 * dt + 4 * lg];
        *(f32x4*)&Op[(size_t)(16 * w + lc) * ND + 16 * dt + 4 * lg] = o;
    }
}

extern "C" void kernel_launch(void* const* d_in, const int* in_sizes, int n_in,
                              void* d_out, int out_size, void* d_ws, size_t ws_size,
                              hipStream_t stream) {
    const float* q = (const float*)d_in[0];
    const float* k = (const float*)d_in[1];
    const float* v = (const float*)d_in[2];
    float* out  = (float*)d_out;
    float* attn = out + (size_t)NB * NH * NS * ND;  // outputs: (output, attn)

    sdpa_kernel<<<dim3((NS / 64) * NB * NH), 256, 0, stream>>>(q, k, v, out, attn);
}

// Round 23
// 78.720 us; speedup vs baseline: 1.1671x; 1.1671x over previous
//
#include <hip/hip_runtime.h>

#define NB 2
#define NH 8
#define NS 2048
#define ND 64
#define WKT 64              // pass-B keys per wave-tile
#define NTW 8               // pass-B tiles per wave (512 / 64)
#define WKA 128             // pass-A keys per wave-tile
#define NTA 4               // pass-A tiles per wave (512 / 128)
#define QST 68              // LDS strides (f16 elems)
#define KST 76
#define VST 68
#define PST 68
#define OST 68              // f32
#define QSCALE 0.18033688f  // 0.125 * log2(e): folds 1/T and exp->exp2

typedef _Float16 f16x4 __attribute__((ext_vector_type(4)));
typedef _Float16 f16x8 __attribute__((ext_vector_type(8)));
typedef float    f32x4 __attribute__((ext_vector_type(4)));

#define MFMA16(A,B,C) __builtin_amdgcn_mfma_f32_16x16x32_f16((A),(B),(C),0,0,0)

static __device__ __forceinline__ f16x8 cat8(f16x4 a, f16x4 b) {
    return __builtin_shufflevector(a, b, 0, 1, 2, 3, 4, 5, 6, 7);
}
static __device__ __forceinline__ f16x4 tof16(float4 f) {
    return (f16x4){ (_Float16)f.x, (_Float16)f.y, (_Float16)f.z, (_Float16)f.w };
}
static __device__ __forceinline__ f16x8 lds8(const _Float16* p) {
    f16x4 a = *(const f16x4*)p;          // ds_read_b64 pair
    f16x4 b = *(const f16x4*)(p + 4);
    return cat8(a, b);
}
// 2^x via compiler intrinsic (raw asm omits TRANS hazard waits -> NaN, r20)
static __device__ __forceinline__ float fexp2(float x) {
    return __builtin_amdgcn_exp2f(x);
}
// wave-local staging fence: wait own LDS ops, pin DS reordering only
static __device__ __forceinline__ void dsfence() {
    asm volatile("s_waitcnt lgkmcnt(0)");
    __builtin_amdgcn_sched_barrier(0x7F);
}

__global__ __launch_bounds__(256, 2)
void sdpa_kernel(const float* __restrict__ Qg, const float* __restrict__ Kg,
                 const float* __restrict__ Vg, float* __restrict__ Og,
                 float* __restrict__ Ag)
{
    const int tid  = threadIdx.x;
    const int w    = tid >> 6;
    const int lane = tid & 63;
    const int lg   = lane >> 4;
    const int lc   = lane & 15;

    // XCD-pinned decode (proven: FETCH 103->12 MB): bid&7 = XCD, 2 heads/XCD.
    const int bid = blockIdx.x;
    const int xcd = bid & 7;
    const int j   = bid >> 3;           // 0..63
    const int bh  = 2 * xcd + (j >> 5); // 0..15
    const int qt_ = j & 31;             // 0..31

    const size_t base = (size_t)bh * NS * ND;
    const float* Qp = Qg + base + (size_t)qt_ * 64 * ND;
    const float* Kp = Kg + base;
    const float* Vp = Vg + base;
    float*       Op = Og + base + (size_t)qt_ * 64 * ND;
    float*       Ap = Ag + (size_t)bh * NS * NS + (size_t)qt_ * 64 * NS;

    // pool 77824 B (2 blocks/CU):
    //   pass A: KA[w] = pool + w*19456 (128 rows x KST76)
    //   pass B: KV[w] = pool + w*9728 (K 64xKST76 / VT 64xVST68 time-shared),
    //           Ps[w] = pool + 38912 + w*8704
    //   overlays: Qs (prologue), MLs (inter-pass, at 38912), Obuf (epilogue)
    __shared__ __align__(16) unsigned char pool[77824];
    _Float16* Qs = (_Float16*)pool;                            // prologue only
    _Float16* KA = (_Float16*)(pool + (size_t)w * 19456);
    _Float16* KV = (_Float16*)(pool + (size_t)w * 9728);
    _Float16* Ps = (_Float16*)(pool + 38912 + (size_t)w * 8704);
    float*   MLs = (float*)(pool + 38912);                     // inter-pass
    float*  Obuf = (float*)pool;                               // epilogue

    // ---- stage Q (scaled by QSCALE = 1/T * log2e) cooperatively ----
    {
        const int srow = tid >> 4, sd0 = (tid & 15) * 4;
        #pragma unroll
        for (int it = 0; it < 4; ++it) {
            const int r = srow + 16 * it;
            float4 f = *(const float4*)&Qp[(size_t)r * ND + sd0];
            f16x4 h = { (_Float16)(f.x * QSCALE), (_Float16)(f.y * QSCALE),
                        (_Float16)(f.z * QSCALE), (_Float16)(f.w * QSCALE) };
            *(f16x4*)&Qs[r * QST + sd0] = h;
        }
    }
    __syncthreads();
    f16x8 qfa[4], qfb[4];        // every wave needs all 64 q columns
    #pragma unroll
    for (int qt = 0; qt < 4; ++qt) {
        qfa[qt] = lds8(&Qs[(16 * qt + lc) * QST + 8 * lg]);
        qfb[qt] = lds8(&Qs[(16 * qt + lc) * QST + 8 * lg + 32]);
    }
    __syncthreads();             // Qs dead; KA overlays it

    const int vkq = lane >> 3;   // V staging: key quad 4*vkq (within 32-half)
    const int vdg = lane & 7;    // V staging: d group 8*vdg

    float lacc[4] = {0.f, 0.f, 0.f, 0.f};

    // ============ PASS A: denominators, WKA=128 (4 big phases) ============
    {
        float4 ka[8], kb[8], kc4[8], kd[8];
        for (int t = 0; t < NTA; ++t) {
            const int koff = 512 * w + WKA * t;
            // issue ALL 32 loads (128 rows) before any cvt -> one vmcnt stall
            #pragma unroll
            for (int i = 0; i < 8; ++i)
                ka[i] = *(const float4*)&Kp[(size_t)koff * ND + i * 256 + 4 * lane];
            #pragma unroll
            for (int i = 0; i < 8; ++i)
                kb[i] = *(const float4*)&Kp[(size_t)koff * ND + 2048 + i * 256 + 4 * lane];
            #pragma unroll
            for (int i = 0; i < 8; ++i)
                kc4[i] = *(const float4*)&Kp[(size_t)koff * ND + 4096 + i * 256 + 4 * lane];
            #pragma unroll
            for (int i = 0; i < 8; ++i)
                kd[i] = *(const float4*)&Kp[(size_t)koff * ND + 6144 + i * 256 + 4 * lane];
            #pragma unroll
            for (int i = 0; i < 8; ++i)
                *(f16x4*)&KA[(4 * i + lg) * KST + 4 * lc] = tof16(ka[i]);
            #pragma unroll
            for (int i = 0; i < 8; ++i)
                *(f16x4*)&KA[(32 + 4 * i + lg) * KST + 4 * lc] = tof16(kb[i]);
            #pragma unroll
            for (int i = 0; i < 8; ++i)
                *(f16x4*)&KA[(64 + 4 * i + lg) * KST + 4 * lc] = tof16(kc4[i]);
            #pragma unroll
            for (int i = 0; i < 8; ++i)
                *(f16x4*)&KA[(96 + 4 * i + lg) * KST + 4 * lc] = tof16(kd[i]);
            dsfence();

            __builtin_amdgcn_s_setprio(1);
            #pragma unroll
            for (int mt = 0; mt < 8; ++mt) {
                f16x8 a0 = lds8(&KA[(16 * mt + lc) * KST + 8 * lg]);
                f16x8 a1 = lds8(&KA[(16 * mt + lc) * KST + 8 * lg + 32]);
                #pragma unroll
                for (int qt = 0; qt < 4; ++qt) {
                    f32x4 z = {0.f, 0.f, 0.f, 0.f};
                    z = MFMA16(a0, qfa[qt], z);
                    z = MFMA16(a1, qfb[qt], z);
                    #pragma unroll
                    for (int r = 0; r < 4; ++r)
                        lacc[qt] += fexp2(z[r]);
                }
            }
            __builtin_amdgcn_s_setprio(0);
            __builtin_amdgcn_sched_barrier(0x7F);   // reads before next writes
        }
    }

    // ---- merge denominators across waves (max-free softmax) ----
    #pragma unroll
    for (int qt = 0; qt < 4; ++qt) {
        lacc[qt] += __shfl_xor(lacc[qt], 16);
        lacc[qt] += __shfl_xor(lacc[qt], 32);
    }
    __syncthreads();             // KA reads done everywhere; MLs region free
    if (lg == 0) {
        #pragma unroll
        for (int qt = 0; qt < 4; ++qt)
            MLs[w * 64 + 16 * qt + lc] = lacc[qt];
    }
    __syncthreads();
    float il[4];
    #pragma unroll
    for (int qt = 0; qt < 4; ++qt)
        il[qt] = 1.0f / (MLs[16 * qt + lc] + MLs[64 + 16 * qt + lc] +
                         MLs[128 + 16 * qt + lc] + MLs[192 + 16 * qt + lc]);
    __syncthreads();             // MLs dead; Ps overlays it

    // ============ PASS B: attn write + PV (r21 + NT attn stores) ============
    f32x4 acc[4][4];             // [dt][qt]
    #pragma unroll
    for (int dt = 0; dt < 4; ++dt)
        #pragma unroll
        for (int qt = 0; qt < 4; ++qt)
            acc[dt][qt] = {0.f, 0.f, 0.f, 0.f};

    float4 kr0[8], kr1[8];
    auto loadK = [&](int koff) {
        #pragma unroll
        for (int i = 0; i < 8; ++i)
            kr0[i] = *(const float4*)&Kp[(size_t)koff * ND + i * 256 + 4 * lane];
        #pragma unroll
        for (int i = 0; i < 8; ++i)
            kr1[i] = *(const float4*)&Kp[(size_t)koff * ND + 2048 + i * 256 + 4 * lane];
    };
    auto writeK = [&]() {
        #pragma unroll
        for (int i = 0; i < 8; ++i)
            *(f16x4*)&KV[(4 * i + lg) * KST + 4 * lc] = tof16(kr0[i]);
        #pragma unroll
        for (int i = 0; i < 8; ++i)
            *(f16x4*)&KV[(32 + 4 * i + lg) * KST + 4 * lc] = tof16(kr1[i]);
    };

    for (int t = 0; t < NTW; ++t) {
        const int koff = 512 * w + WKT * t;
        loadK(koff);
        writeK();                // K into KV (kr dies here)
        // ---- issue V loads for both 32-key halves (land during QK^T) ----
        float4 vr0[8], vr1[8];
        #pragma unroll
        for (int r = 0; r < 4; ++r)
            #pragma unroll
            for (int h = 0; h < 2; ++h) {
                vr0[2 * r + h] = *(const float4*)
                    &Vp[(size_t)(koff + 4 * vkq + r) * ND + 8 * vdg + 4 * h];
                vr1[2 * r + h] = *(const float4*)
                    &Vp[(size_t)(koff + 32 + 4 * vkq + r) * ND + 8 * vdg + 4 * h];
            }
        dsfence();               // K writes visible to own reads

        // ---- QK^T -> 2^z -> Ps (per-mt fused, low VGPR) ----
        __builtin_amdgcn_s_setprio(1);
        #pragma unroll
        for (int mt = 0; mt < 4; ++mt) {
            f16x8 a0 = lds8(&KV[(16 * mt + lc) * KST + 8 * lg]);
            f16x8 a1 = lds8(&KV[(16 * mt + lc) * KST + 8 * lg + 32]);
            #pragma unroll
            for (int qt = 0; qt < 4; ++qt) {
                f32x4 z = {0.f, 0.f, 0.f, 0.f};
                z = MFMA16(a0, qfa[qt], z);
                z = MFMA16(a1, qfb[qt], z);
                f32x4 p;
                #pragma unroll
                for (int r = 0; r < 4; ++r)
                    p[r] = fexp2(z[r]) * il[qt];
                f16x4 ph = { (_Float16)p[0], (_Float16)p[1],
                             (_Float16)p[2], (_Float16)p[3] };
                *(f16x4*)&Ps[(16 * qt + lc) * PST + 16 * mt + 4 * lg] = ph;
            }
        }
        __builtin_amdgcn_s_setprio(0);

        // ---- VT writes into KV (after QK's last read; wave-local DS in-order) ----
        #pragma unroll
        for (int h = 0; h < 2; ++h)
            #pragma unroll
            for (int jj = 0; jj < 4; ++jj) {
                f16x4 c0 = { (_Float16)vr0[0 + h][jj], (_Float16)vr0[2 + h][jj],
                             (_Float16)vr0[4 + h][jj], (_Float16)vr0[6 + h][jj] };
                *(f16x4*)&KV[(8 * vdg + 4 * h + jj) * VST + 4 * vkq] = c0;
                f16x4 c1 = { (_Float16)vr1[0 + h][jj], (_Float16)vr1[2 + h][jj],
                             (_Float16)vr1[4 + h][jj], (_Float16)vr1[6 + h][jj] };
                *(f16x4*)&KV[(8 * vdg + 4 * h + jj) * VST + 32 + 4 * vkq] = c1;
            }
        dsfence();               // Ps + VT visible to own reads

        // ---- PV: O^T += V^T . P^T (two 32-key slices) ----
        f16x8 bfa[4], bfb[4];
        #pragma unroll
        for (int qt = 0; qt < 4; ++qt) {
            bfa[qt] = lds8(&Ps[(16 * qt + lc) * PST + 8 * lg]);
            bfb[qt] = lds8(&Ps[(16 * qt + lc) * PST + 32 + 8 * lg]);
        }
        __builtin_amdgcn_s_setprio(1);
        #pragma unroll
        for (int dt = 0; dt < 4; ++dt) {
            f16x8 af0 = lds8(&KV[(16 * dt + lc) * VST + 8 * lg]);
            f16x8 af1 = lds8(&KV[(16 * dt + lc) * VST + 32 + 8 * lg]);
            #pragma unroll
            for (int qt = 0; qt < 4; ++qt) {
                acc[dt][qt] = MFMA16(af0, bfa[qt], acc[dt][qt]);
                acc[dt][qt] = MFMA16(af1, bfb[qt], acc[dt][qt]);
            }
        }
        __builtin_amdgcn_s_setprio(0);

        // ---- attn store: Ps readback, cvt, 256B/row, NONTEMPORAL (L2 bypass:
        // 256MB write stream can't merge in 4MB/XCD L2 and evicts K/V) ----
        #pragma unroll
        for (int i = 0; i < 16; ++i) {
            const int qr = 4 * i + (lane >> 4);    // 0..63
            const int kc = 4 * (lane & 15);        // 0..60
            f16x4 ph = *(const f16x4*)&Ps[qr * PST + kc];
            f32x4 pf = { (float)ph[0], (float)ph[1], (float)ph[2], (float)ph[3] };
            __builtin_nontemporal_store(
                pf, (f32x4*)&Ap[(size_t)qr * NS + koff + kc]);
        }
        __builtin_amdgcn_sched_barrier(0x7F);   // reads precede next-tile writes
    }

    // ---- merge partial O across waves (sequential LDS accumulate), store ----
    __syncthreads();             // main-loop LDS dead; Obuf overlays
    #pragma unroll
    for (int ww = 0; ww < 4; ++ww) {
        if (w == ww) {
            #pragma unroll
            for (int dt = 0; dt < 4; ++dt)
                #pragma unroll
                for (int qt = 0; qt < 4; ++qt) {
                    float* ad = &Obuf[(16 * qt + lc) * OST + 16 * dt + 4 * lg];
                    f32x4 v = acc[dt][qt];
                    if (ww > 0) v = v + *(const f32x4*)ad;
                    *(f32x4*)ad = v;
                }
        }
        __syncthreads();
    }
    #pragma unroll
    for (int dt = 0; dt < 4; ++dt) {
        f32x4 o = *(const f32x4*)&Obuf[(16 * w + lc) * OST + 16 * dt + 4 * lg];
        *(f32x4*)&Op[(size_t)(16 * w + lc) * ND + 16 * dt + 4 * lg] = o;
    }
}

extern "C" void kernel_launch(void* const* d_in, const int* in_sizes, int n_in,
                              void* d_out, int out_size, void* d_ws, size_t ws_size,
                              hipStream_t stream) {
    const float* q = (const float*)d_in[0];
    const float* k = (const float*)d_in[1];
    const float* v = (const float*)d_in[2];
    float* out  = (float*)d_out;
    float* attn = out + (size_t)NB * NH * NS * ND;  // outputs: (output, attn)

    sdpa_kernel<<<dim3((NS / 64) * NB * NH), 256, 0, stream>>>(q, k, v, out, attn);
}